// Round 2
// baseline (514.456 us; speedup 1.0000x reference)
//
#include <hip/hip_runtime.h>

// Problem constants
#define DD   512
#define KK_N 32
#define HH   4
#define DH   128
#define BN_TOT 4096

typedef __bf16 bf16x8 __attribute__((ext_vector_type(8)));
typedef float  f32x4  __attribute__((ext_vector_type(4)));
typedef unsigned short u16;

__device__ __forceinline__ unsigned rne_bf16(float x) {
    unsigned u = __float_as_uint(x);
    return (u + 0x7fffu + ((u >> 16) & 1u)) >> 16;
}
__device__ __forceinline__ float bf16_f(unsigned h16) {   // low 16 bits = bf16
    return __uint_as_float(h16 << 16);
}

// ---------------------------------------------------------------------------
// One-shot fp32 -> (hi,lo) bf16 plane conversion for x, Wq, Wv (3 segments).
// Grid covers n0+n1+n2 float4s exactly.
// ---------------------------------------------------------------------------
__global__ __launch_bounds__(256)
void cvt3(const float4* __restrict__ s0, u16* __restrict__ h0, u16* __restrict__ l0, int n0,
          const float4* __restrict__ s1, u16* __restrict__ h1, u16* __restrict__ l1, int n1,
          const float4* __restrict__ s2, u16* __restrict__ h2, u16* __restrict__ l2, int n2)
{
    int i = blockIdx.x * 256 + threadIdx.x;
    const float4* s; u16* ph; u16* pl;
    if (i < n0)                { s = s0; ph = h0; pl = l0; }
    else if (i < n0 + n1)      { i -= n0;      s = s1; ph = h1; pl = l1; }
    else if (i < n0 + n1 + n2) { i -= n0 + n1; s = s2; ph = h2; pl = l2; }
    else return;
    float4 v = s[i];
    unsigned a = rne_bf16(v.x), b = rne_bf16(v.y), c = rne_bf16(v.z), d = rne_bf16(v.w);
    float lx = v.x - bf16_f(a), ly = v.y - bf16_f(b);
    float lz = v.z - bf16_f(c), lw = v.w - bf16_f(d);
    *(uint2*)&ph[(long)i * 4] = make_uint2(a | (b << 16), c | (d << 16));
    *(uint2*)&pl[(long)i * 4] = make_uint2(rne_bf16(lx) | (rne_bf16(ly) << 16),
                                           rne_bf16(lz) | (rne_bf16(lw) << 16));
}

// ---------------------------------------------------------------------------
// One-time prep: WkT[h][o][k] = Wk[h*128 + k][o], output as bf16 hi/lo planes.
// grid (16, 4). LDS-tiled transpose.
// ---------------------------------------------------------------------------
__global__ __launch_bounds__(256)
void prep_wkT(const float* __restrict__ Wk, u16* __restrict__ WkTh, u16* __restrict__ WkTl)
{
    __shared__ float tile[32][DH + 1];
    const int h = blockIdx.y, o0 = blockIdx.x * 32, t = threadIdx.x;
#pragma unroll
    for (int r = 0; r < 16; r++) {
        int k = (t >> 5) + r * 8;                       // 0..127
        tile[t & 31][k] = Wk[(long)(h * DH + k) * DD + o0 + (t & 31)];
    }
    __syncthreads();
#pragma unroll
    for (int r = 0; r < 16; r++) {
        int ol = (t >> 7) + r * 2;                      // 0..31
        int k  = t & 127;
        float v = tile[ol][k];
        unsigned hb = rne_bf16(v);
        long o = ((long)h * DD + o0 + ol) * DH + k;
        WkTh[o] = (u16)hb;
        WkTl[o] = (u16)rne_bf16(v - bf16_f(hb));
    }
}

// ---------------------------------------------------------------------------
// bf16x2-split MFMA GEMM (NT) on PRE-CONVERTED hi/lo planes:
//   C[r][o] = sum_k A[r][k]*B[o][k] (+bias[o]),  A = Ah+Al, B = Bh+Bl
// math = Ah*Bh + Ah*Bl + Al*Bh on v_mfma_f32_16x16x32_bf16 (lo*lo dropped).
// Staging is pure load->ds_write (no conversion VALU). Output optionally fp32
// (Cf) and/or bf16 hi/lo planes (Ch/Cl) for the next consumer.
// LDS row: k-group g at shorts [g*16 .. g*16+7]=hi, [+8..+15]=lo; row stride
// LDW = 136 shorts (272 B) -> fragment ds_read_b128 conflict-free.
// ---------------------------------------------------------------------------
template<int BM, int BN>
__global__ __launch_bounds__(256)
void gemm_pre(const u16* __restrict__ Ah, const u16* __restrict__ Al, int lda, long sA,
              const u16* __restrict__ Bh, const u16* __restrict__ Bl, int ldb, long sB,
              float* __restrict__ Cf, int ldc, long sC,
              u16* __restrict__ Ch, u16* __restrict__ Cl, int ldch, long sCh,
              const float* __restrict__ bias, int sBias, int Kd)
{
    constexpr int BK  = 64;
    constexpr int LDW = 2 * BK + 8;                 // 136 shorts per row
    constexpr int AL = BM / 32;                     // 16B chunks/thread/plane
    constexpr int BL = BN / 32;
    constexpr int WM = BM / 2, WN = BN / 2;
    constexpr int MI = WM / 16, NI = WN / 16;

    const int z = blockIdx.z;
    Ah += (long)z * sA;  Al += (long)z * sA;
    Bh += (long)z * sB;  Bl += (long)z * sB;
    if (Cf)   Cf += (long)z * sC;
    if (Ch) { Ch += (long)z * sCh; Cl += (long)z * sCh; }
    if (bias) bias += (long)z * sBias;

    __shared__ __align__(16) u16 As[BM * LDW];
    __shared__ __align__(16) u16 Bs[BN * LDW];

    const int t    = threadIdx.x;
    const int lane = t & 63;
    const int wave = t >> 6;
    const int wm   = wave >> 1, wn = wave & 1;
    const int rbase = blockIdx.y * BM;
    const int obase = blockIdx.x * BN;

    uint4 avh[AL], avl[AL], bvh[BL], bvl[BL];
    auto loadAB = [&](int k0) {
#pragma unroll
        for (int i = 0; i < AL; i++) {
            int s = t + i * 256, kg = s & 7, row = s >> 3;
            long off = (long)(rbase + row) * lda + k0 + kg * 8;
            avh[i] = *(const uint4*)&Ah[off];
            avl[i] = *(const uint4*)&Al[off];
        }
#pragma unroll
        for (int i = 0; i < BL; i++) {
            int s = t + i * 256, kg = s & 7, row = s >> 3;
            long off = (long)(obase + row) * ldb + k0 + kg * 8;
            bvh[i] = *(const uint4*)&Bh[off];
            bvl[i] = *(const uint4*)&Bl[off];
        }
    };

    f32x4 acc[MI][NI];
#pragma unroll
    for (int m = 0; m < MI; m++)
#pragma unroll
        for (int n = 0; n < NI; n++)
            acc[m][n] = (f32x4){0.f, 0.f, 0.f, 0.f};

    // fragment base: row/col = lane&15 within 16x16, k-block = (lane>>4)*8
    const int a_base = (wm * WM + (lane & 15)) * LDW + (lane >> 4) * 16;
    const int b_base = (wn * WN + (lane & 15)) * LDW + (lane >> 4) * 16;

    loadAB(0);
    for (int k0 = 0; k0 < Kd; k0 += BK) {
        __syncthreads();
#pragma unroll
        for (int i = 0; i < AL; i++) {
            int s = t + i * 256, kg = s & 7, row = s >> 3;
            int off = row * LDW + kg * 16;
            *(uint4*)&As[off]     = avh[i];
            *(uint4*)&As[off + 8] = avl[i];
        }
#pragma unroll
        for (int i = 0; i < BL; i++) {
            int s = t + i * 256, kg = s & 7, row = s >> 3;
            int off = row * LDW + kg * 16;
            *(uint4*)&Bs[off]     = bvh[i];
            *(uint4*)&Bs[off + 8] = bvl[i];
        }
        __syncthreads();
        if (k0 + BK < Kd) loadAB(k0 + BK);   // prefetch overlaps compute

#pragma unroll
        for (int ks = 0; ks < 2; ks++) {
            bf16x8 ah[MI], al[MI], bh[NI], bl[NI];
#pragma unroll
            for (int m = 0; m < MI; m++) {
                ah[m] = *(const bf16x8*)&As[a_base + m * 16 * LDW + ks * 64];
                al[m] = *(const bf16x8*)&As[a_base + m * 16 * LDW + ks * 64 + 8];
            }
#pragma unroll
            for (int n = 0; n < NI; n++) {
                bh[n] = *(const bf16x8*)&Bs[b_base + n * 16 * LDW + ks * 64];
                bl[n] = *(const bf16x8*)&Bs[b_base + n * 16 * LDW + ks * 64 + 8];
            }
#pragma unroll
            for (int m = 0; m < MI; m++)
#pragma unroll
                for (int n = 0; n < NI; n++)
                    acc[m][n] = __builtin_amdgcn_mfma_f32_16x16x32_bf16(ah[m], bh[n], acc[m][n], 0, 0, 0);
#pragma unroll
            for (int m = 0; m < MI; m++)
#pragma unroll
                for (int n = 0; n < NI; n++)
                    acc[m][n] = __builtin_amdgcn_mfma_f32_16x16x32_bf16(ah[m], bl[n], acc[m][n], 0, 0, 0);
#pragma unroll
            for (int m = 0; m < MI; m++)
#pragma unroll
                for (int n = 0; n < NI; n++)
                    acc[m][n] = __builtin_amdgcn_mfma_f32_16x16x32_bf16(al[m], bh[n], acc[m][n], 0, 0, 0);
        }
    }

    // epilogue: C/D layout col = lane&15, row = (lane>>4)*4 + reg  [m89-verified]
#pragma unroll
    for (int n = 0; n < NI; n++) {
        int col = obase + wn * WN + n * 16 + (lane & 15);
        float bv_ = bias ? bias[col] : 0.f;
#pragma unroll
        for (int m = 0; m < MI; m++) {
            int row0 = rbase + wm * WM + m * 16 + (lane >> 4) * 4;
#pragma unroll
            for (int j = 0; j < 4; j++) {
                float val = acc[m][n][j] + bv_;
                if (Cf) Cf[(long)(row0 + j) * ldc + col] = val;
                if (Ch) {
                    unsigned hb = rne_bf16(val);
                    long o = (long)(row0 + j) * ldch + col;
                    Ch[o] = (u16)hb;
                    Cl[o] = (u16)rne_bf16(val - bf16_f(hb));
                }
            }
        }
    }
}

// ---------------------------------------------------------------------------
// Fused scores -> masked online softmax -> attention-weighted embedding sum.
// One block per (b,n). q comes in as bf16 hi/lo planes; wne goes out as bf16
// hi/lo planes (identical values to the fp32->bf16x2 split GEMM-4 used to do).
// Weighted phase: lane l owns columns {4l..4l+3} and {256+4l..256+4l+3} so each
// consecutive-8-lane ds_read_b128 group covers all 32 banks (conflict-free).
// ---------------------------------------------------------------------------
__global__ __launch_bounds__(256)
void attn_fused(const float* __restrict__ ne,    // [BN][32][512]
                const int*   __restrict__ mask,  // [BN][32]
                const u16*   __restrict__ qh,    // [BN][512] bf16 hi
                const u16*   __restrict__ ql,    // [BN][512] bf16 lo
                const float* __restrict__ g,     // [BN][4][512]
                const float* __restrict__ bk,    // [512]
                u16* __restrict__ wh,            // [BN][4][512] bf16 hi
                u16* __restrict__ wl)            // [BN][4][512] bf16 lo
{
    const int bn   = blockIdx.x;
    const int t    = threadIdx.x;
    const int wave = t >> 6;
    const int lane = t & 63;

    __shared__ __align__(16) float ne_s[16][516];   // chunk of 16 neighbors, padded
    __shared__ __align__(16) float g_s[HH * DD];
    __shared__ float part[4][16][HH];               // [wave][k][h]
    __shared__ float p_s[HH][16];
    __shared__ float c_s[HH];
    __shared__ float m_s[HH], l_s[HH], alpha_s[HH];

    // stage g (query-side projected vectors), 2048 floats
    {
        const float4* gs = (const float4*)(g + (long)bn * (HH * DD));
        float4 v0 = gs[t];
        float4 v1 = gs[t + 256];
        *(float4*)&g_s[t * 4]         = v0;
        *(float4*)&g_s[(t + 256) * 4] = v1;
    }
    // c[h] = q_h . bk_h   (wave w handles head w; 64 lanes x 2 elems = 128)
    {
        long qoff = (long)bn * DD + wave * DH + lane * 2;
        unsigned uh = *(const unsigned*)&qh[qoff];
        unsigned ul = *(const unsigned*)&ql[qoff];
        float qx = __uint_as_float(uh << 16) + __uint_as_float(ul << 16);
        float qy = __uint_as_float(uh & 0xffff0000u) + __uint_as_float(ul & 0xffff0000u);
        float2 b2 = *(const float2*)&bk[wave * DH + lane * 2];
        float cp = qx * b2.x + qy * b2.y;
#pragma unroll
        for (int off = 32; off >= 1; off >>= 1)
            cp += __shfl_xor(cp, off, 64);
        if (lane == 0) c_s[wave] = cp;
    }
    if (t < HH) { m_s[t] = -__builtin_inff(); l_s[t] = 0.f; }

    float wacc[8] = {};
    const int h_own = t >> 6;            // head owned in weighted-sum phase
    const int dlo   = (t & 63) * 4;      // columns dlo.. and 256+dlo..
    const int kk    = t & 15;            // neighbor within chunk (scores phase)
    const int rep   = t >> 4;            // D-slice 32 floats (scores phase)

    for (int ch = 0; ch < 2; ch++) {
        __syncthreads();
        // load chunk of 16 neighbor rows (contiguous 32 KB) into LDS
        {
            const float4* src = (const float4*)(ne + (long)bn * (KK_N * DD) + ch * (16 * DD));
#pragma unroll
            for (int i = 0; i < 8; i++) {
                int f = i * 256 + t;
                float4 v = src[f];
                *(float4*)&ne_s[f >> 7][(f & 127) * 4] = v;
            }
        }
        __syncthreads();
        // scores: 16 k x 4 h dot products of length 512, split 16 ways over D
        {
            float acc[HH] = {};
#pragma unroll
            for (int i = 0; i < 8; i++) {
                float4 nv = *(const float4*)&ne_s[kk][rep * 32 + i * 4];
#pragma unroll
                for (int h = 0; h < HH; h++) {
                    float4 gv = *(const float4*)&g_s[h * DD + rep * 32 + i * 4];
                    acc[h] = fmaf(nv.x, gv.x, acc[h]);
                    acc[h] = fmaf(nv.y, gv.y, acc[h]);
                    acc[h] = fmaf(nv.z, gv.z, acc[h]);
                    acc[h] = fmaf(nv.w, gv.w, acc[h]);
                }
            }
#pragma unroll
            for (int h = 0; h < HH; h++) {
                acc[h] += __shfl_xor(acc[h], 16, 64);
                acc[h] += __shfl_xor(acc[h], 32, 64);
            }
            if ((t & 48) == 0) {
#pragma unroll
                for (int h = 0; h < HH; h++) part[wave][kk][h] = acc[h];
            }
        }
        __syncthreads();
        // online softmax update (wave 0 only; lanes: k_i = bits 0..3, h = bits 4..5)
        if (t < 64) {
            int k_i = t & 15, h = t >> 4;
            float s = part[0][k_i][h] + part[1][k_i][h] + part[2][k_i][h]
                    + part[3][k_i][h] + c_s[h];
            if (mask[(long)bn * KK_N + ch * 16 + k_i] == 0) s = -1.0e9f;
            float mx = s;
#pragma unroll
            for (int off = 8; off >= 1; off >>= 1)
                mx = fmaxf(mx, __shfl_xor(mx, off, 64));
            float m_old = m_s[h];
            float m_new = fmaxf(m_old, mx);
            float p = expf(s - m_new);
            float sm = p;
#pragma unroll
            for (int off = 8; off >= 1; off >>= 1)
                sm += __shfl_xor(sm, off, 64);
            p_s[h][k_i] = p;
            if (k_i == 0) {
                float alpha = expf(m_old - m_new);
                alpha_s[h] = alpha;
                l_s[h] = l_s[h] * alpha + sm;
                m_s[h] = m_new;
            }
        }
        __syncthreads();
        // weighted accumulate: thread owns (h_own, cols dlo..+3 and 256+dlo..+3)
        {
            float alpha = alpha_s[h_own];
#pragma unroll
            for (int j = 0; j < 8; j++) wacc[j] *= alpha;
#pragma unroll
            for (int k2 = 0; k2 < 16; k2++) {
                float pk = p_s[h_own][k2];
                float4 n0 = *(const float4*)&ne_s[k2][dlo];
                float4 n1 = *(const float4*)&ne_s[k2][256 + dlo];
                wacc[0] = fmaf(pk, n0.x, wacc[0]);
                wacc[1] = fmaf(pk, n0.y, wacc[1]);
                wacc[2] = fmaf(pk, n0.z, wacc[2]);
                wacc[3] = fmaf(pk, n0.w, wacc[3]);
                wacc[4] = fmaf(pk, n1.x, wacc[4]);
                wacc[5] = fmaf(pk, n1.y, wacc[5]);
                wacc[6] = fmaf(pk, n1.z, wacc[6]);
                wacc[7] = fmaf(pk, n1.w, wacc[7]);
            }
        }
    }
    // finalize: normalize and write wne hi/lo planes
    float rl = 1.0f / l_s[h_own];
    long b0 = (long)bn * (HH * DD) + h_own * DD + dlo;
    unsigned hw[8], lw[8];
#pragma unroll
    for (int j = 0; j < 8; j++) {
        float val = wacc[j] * rl;
        hw[j] = rne_bf16(val);
        lw[j] = rne_bf16(val - bf16_f(hw[j]));
    }
    *(uint2*)&wh[b0]       = make_uint2(hw[0] | (hw[1] << 16), hw[2] | (hw[3] << 16));
    *(uint2*)&wl[b0]       = make_uint2(lw[0] | (lw[1] << 16), lw[2] | (lw[3] << 16));
    *(uint2*)&wh[b0 + 256] = make_uint2(hw[4] | (hw[5] << 16), hw[6] | (hw[7] << 16));
    *(uint2*)&wl[b0 + 256] = make_uint2(lw[4] | (lw[5] << 16), lw[6] | (lw[7] << 16));
}

// ---------------------------------------------------------------------------
extern "C" void kernel_launch(void* const* d_in, const int* in_sizes, int n_in,
                              void* d_out, int out_size, void* d_ws, size_t ws_size,
                              hipStream_t stream) {
    (void)in_sizes; (void)n_in; (void)out_size; (void)ws_size;
    const float* ne  = (const float*)d_in[0];
    const int*   msk = (const int*)  d_in[1];
    const float* x   = (const float*)d_in[2];
    const float* Wq  = (const float*)d_in[3];
    const float* bq  = (const float*)d_in[4];
    const float* Wk  = (const float*)d_in[5];
    const float* bk  = (const float*)d_in[6];
    const float* Wv  = (const float*)d_in[7];
    const float* bv  = (const float*)d_in[8];
    float* out = (float*)d_out;

    const long NQ = (long)BN_TOT * DD;        // 2,097,152
    const long NW = (long)DD * DD;            //   262,144
    const long NG = (long)BN_TOT * HH * DD;   // 8,388,608

    char* ws = (char*)d_ws;
    u16* xh   = (u16*)ws;              ws += NQ * 2;
    u16* xl   = (u16*)ws;              ws += NQ * 2;
    u16* wqh  = (u16*)ws;              ws += NW * 2;
    u16* wql  = (u16*)ws;              ws += NW * 2;
    u16* wvh  = (u16*)ws;              ws += NW * 2;
    u16* wvl  = (u16*)ws;              ws += NW * 2;
    u16* wkTh = (u16*)ws;              ws += NW * 2;
    u16* wkTl = (u16*)ws;              ws += NW * 2;
    u16* qh   = (u16*)ws;              ws += NQ * 2;
    u16* ql   = (u16*)ws;              ws += NQ * 2;
    u16* wneh = (u16*)ws;              ws += NG * 2;
    u16* wnel = (u16*)ws;              ws += NG * 2;
    float* g_ws = (float*)ws;          // 32 MB

    dim3 blk(256);
    const int n4x = (int)(NQ / 4), n4w = (int)(NW / 4);
    // 0a) convert x, Wq, Wv to bf16 hi/lo planes (one pass)
    cvt3<<<dim3((n4x + 2 * n4w) / 256), blk, 0, stream>>>(
        (const float4*)x,  xh,  xl,  n4x,
        (const float4*)Wq, wqh, wql, n4w,
        (const float4*)Wv, wvh, wvl, n4w);
    // 0b) WkT[h][o][k] = Wk[h*128+k][o] as bf16 hi/lo planes
    prep_wkT<<<dim3(16, HH), blk, 0, stream>>>(Wk, wkTh, wkTl);
    // 1) q = x @ Wq^T + bq -> bf16 hi/lo planes   M=4096 N=512 K=512
    gemm_pre<64, 128><<<dim3(DD / 128, BN_TOT / 64, 1), blk, 0, stream>>>(
        xh, xl, DD, 0, wqh, wql, DD, 0,
        nullptr, 0, 0, qh, ql, DD, 0, bq, 0, DD);
    // 2) g[:,h,:] = q_h @ WkT[h]^T (fp32 out)     per head M=4096 N=512 K=128
    gemm_pre<64, 128><<<dim3(DD / 128, BN_TOT / 64, HH), blk, 0, stream>>>(
        qh, ql, DD, DH, wkTh, wkTl, DH, (long)DD * DH,
        g_ws, HH * DD, DD, nullptr, nullptr, 0, 0, nullptr, 0, DH);
    // 3) fused scores/softmax/weighted-sum -> wne hi/lo planes
    attn_fused<<<dim3(BN_TOT), blk, 0, stream>>>(ne, msk, qh, ql, g_ws, bk, wneh, wnel);
    // 4) out[:,h*128:] = wne_h @ Wv_h^T + bv_h    per head M=4096 N=128 K=512
    gemm_pre<64, 128><<<dim3(1, BN_TOT / 64, HH), blk, 0, stream>>>(
        wneh, wnel, HH * DD, DD, wvh, wvl, DD, (long)DH * DD,
        out, DD, DH, nullptr, nullptr, 0, 0, bv, DH, DD);
}

// Round 3
// 503.995 us; speedup vs baseline: 1.0208x; 1.0208x over previous
//
#include <hip/hip_runtime.h>

// Problem constants
#define DD   512
#define KK_N 32
#define HH   4
#define DH   128
#define BN_TOT 4096

typedef __bf16 bf16x8 __attribute__((ext_vector_type(8)));
typedef float  f32x4  __attribute__((ext_vector_type(4)));
typedef unsigned short u16;

__device__ __forceinline__ unsigned rne_bf16(float x) {
    unsigned u = __float_as_uint(x);
    return (u + 0x7fffu + ((u >> 16) & 1u)) >> 16;
}
__device__ __forceinline__ float bf16_f(unsigned h16) {   // low 16 bits = bf16
    return __uint_as_float(h16 << 16);
}

// ---------------------------------------------------------------------------
// P0: single prep dispatch.
//  blocks 0..2559   : linear fp32 -> (hi,lo) bf16 planes for x, Wq, Wv
//  blocks 2560..2623: WkT[h][o][k] = Wk[h*128+k][o] as bf16 hi/lo planes
// ---------------------------------------------------------------------------
__global__ __launch_bounds__(256)
void prep(const float4* __restrict__ x,  u16* __restrict__ xh,  u16* __restrict__ xl,
          const float4* __restrict__ Wq, u16* __restrict__ wqh, u16* __restrict__ wql,
          const float4* __restrict__ Wv, u16* __restrict__ wvh, u16* __restrict__ wvl,
          const float*  __restrict__ Wk, u16* __restrict__ wkTh, u16* __restrict__ wkTl)
{
    __shared__ float tile[32][DH + 1];
    const int b = blockIdx.x, t = threadIdx.x;
    if (b < 2560) {
        int i = b * 256 + t;                       // 0 .. 655359
        const float4* s; u16* ph; u16* pl;
        if (i < 524288)      { s = x;  ph = xh;  pl = xl;  }
        else if (i < 589824) { i -= 524288; s = Wq; ph = wqh; pl = wql; }
        else                 { i -= 589824; s = Wv; ph = wvh; pl = wvl; }
        float4 v = s[i];
        unsigned a = rne_bf16(v.x), bb = rne_bf16(v.y), c = rne_bf16(v.z), d = rne_bf16(v.w);
        float lx = v.x - bf16_f(a), ly = v.y - bf16_f(bb);
        float lz = v.z - bf16_f(c), lw = v.w - bf16_f(d);
        *(uint2*)&ph[(long)i * 4] = make_uint2(a | (bb << 16), c | (d << 16));
        *(uint2*)&pl[(long)i * 4] = make_uint2(rne_bf16(lx) | (rne_bf16(ly) << 16),
                                               rne_bf16(lz) | (rne_bf16(lw) << 16));
        return;
    }
    // transpose part
    const int tb = b - 2560;                       // 0..63
    const int h = tb >> 4, o0 = (tb & 15) * 32;
#pragma unroll
    for (int r = 0; r < 16; r++) {
        int k = (t >> 5) + r * 8;                  // 0..127
        tile[t & 31][k] = Wk[(long)(h * DH + k) * DD + o0 + (t & 31)];
    }
    __syncthreads();
#pragma unroll
    for (int r = 0; r < 16; r++) {
        int ol = (t >> 7) + r * 2;                 // 0..31
        int k  = t & 127;
        float v = tile[ol][k];
        unsigned hb = rne_bf16(v);
        long o = ((long)h * DD + o0 + ol) * DH + k;
        wkTh[o] = (u16)hb;
        wkTl[o] = (u16)rne_bf16(v - bf16_f(hb));
    }
}

// ---------------------------------------------------------------------------
// D1: fused q+g per (32-row tile, head h):
//   q_h[32][128] = x[32][512] @ Wq_h^T + bq_h      (kept in LDS as hi/lo)
//   c[row][h]    = q_h[row] . bk_h                 (written to c_ws)
//   g_h[32][512] = q_h @ WkT_h^T                   (fp32 to g_ws)
// bf16x2-split on v_mfma_f32_16x16x32_bf16; waves 1x4 (WM=32, WN=32).
// Grid (128, 4). LDS ~60KB -> 2 blocks/CU, 8 waves/CU.
// ---------------------------------------------------------------------------
__global__ __launch_bounds__(256)
void qg_fused(const u16* __restrict__ xh,  const u16* __restrict__ xl,
              const u16* __restrict__ wqh, const u16* __restrict__ wql,
              const u16* __restrict__ wkTh, const u16* __restrict__ wkTl,
              const float* __restrict__ bq, const float* __restrict__ bk,
              float* __restrict__ g, float* __restrict__ c_ws)
{
    constexpr int LDW = 2 * 64 + 8;    // 136 shorts: K=64 staging row
    constexpr int LDQ = 2 * 128 + 8;   // 264 shorts: q_s row (K=128)

    const int h  = blockIdx.y;
    const int r0 = blockIdx.x * 32;

    __shared__ __align__(16) u16 As[32 * LDW];    // 8.5 KB
    __shared__ __align__(16) u16 Bs[128 * LDW];   // 34 KB (phase1 Wq / phase2 WkT)
    __shared__ __align__(16) u16 q_s[32 * LDQ];   // 16.5 KB

    const int t = threadIdx.x, lane = t & 63, wn = t >> 6;

    // fragment bases (A rows shared by all waves; B col-block per wave)
    const int abase = (lane & 15) * LDW + (lane >> 4) * 16;
    const int bbase = (wn * 32 + (lane & 15)) * LDW + (lane >> 4) * 16;

    // ---------------- phase 1: q ----------------
    uint4 avh, avl, bvh[4], bvl[4];
    auto load1 = [&](int k0) {
        { int kg = t & 7, row = t >> 3;
          long o = (long)(r0 + row) * DD + k0 + kg * 8;
          avh = *(const uint4*)&xh[o]; avl = *(const uint4*)&xl[o]; }
#pragma unroll
        for (int i = 0; i < 4; i++) {
            int s = t + i * 256, kg = s & 7, row = s >> 3;
            long o = (long)(h * DH + row) * DD + k0 + kg * 8;
            bvh[i] = *(const uint4*)&wqh[o]; bvl[i] = *(const uint4*)&wql[o];
        }
    };

    f32x4 acc[2][2];
#pragma unroll
    for (int m = 0; m < 2; m++)
#pragma unroll
        for (int n = 0; n < 2; n++) acc[m][n] = (f32x4){0.f, 0.f, 0.f, 0.f};

    load1(0);
    for (int k0 = 0; k0 < DD; k0 += 64) {
        __syncthreads();
        { int kg = t & 7, row = t >> 3, off = row * LDW + kg * 16;
          *(uint4*)&As[off] = avh; *(uint4*)&As[off + 8] = avl; }
#pragma unroll
        for (int i = 0; i < 4; i++) {
            int s = t + i * 256, kg = s & 7, row = s >> 3, off = row * LDW + kg * 16;
            *(uint4*)&Bs[off] = bvh[i]; *(uint4*)&Bs[off + 8] = bvl[i];
        }
        __syncthreads();
        if (k0 + 64 < DD) load1(k0 + 64);
#pragma unroll
        for (int ks = 0; ks < 2; ks++) {
            bf16x8 ah[2], al[2], bh[2], bl[2];
#pragma unroll
            for (int m = 0; m < 2; m++) {
                ah[m] = *(const bf16x8*)&As[abase + m * 16 * LDW + ks * 64];
                al[m] = *(const bf16x8*)&As[abase + m * 16 * LDW + ks * 64 + 8];
            }
#pragma unroll
            for (int n = 0; n < 2; n++) {
                bh[n] = *(const bf16x8*)&Bs[bbase + n * 16 * LDW + ks * 64];
                bl[n] = *(const bf16x8*)&Bs[bbase + n * 16 * LDW + ks * 64 + 8];
            }
#pragma unroll
            for (int m = 0; m < 2; m++)
#pragma unroll
                for (int n = 0; n < 2; n++)
                    acc[m][n] = __builtin_amdgcn_mfma_f32_16x16x32_bf16(ah[m], bh[n], acc[m][n], 0, 0, 0);
#pragma unroll
            for (int m = 0; m < 2; m++)
#pragma unroll
                for (int n = 0; n < 2; n++)
                    acc[m][n] = __builtin_amdgcn_mfma_f32_16x16x32_bf16(ah[m], bl[n], acc[m][n], 0, 0, 0);
#pragma unroll
            for (int m = 0; m < 2; m++)
#pragma unroll
                for (int n = 0; n < 2; n++)
                    acc[m][n] = __builtin_amdgcn_mfma_f32_16x16x32_bf16(al[m], bh[n], acc[m][n], 0, 0, 0);
        }
    }
    // epilogue -> q_s planes (+bq); C/D layout: col=lane&15, row=(lane>>4)*4+j
#pragma unroll
    for (int m = 0; m < 2; m++)
#pragma unroll
        for (int n = 0; n < 2; n++) {
            int col = wn * 32 + n * 16 + (lane & 15);      // 0..127
            float bqv = bq[h * DH + col];
#pragma unroll
            for (int j = 0; j < 4; j++) {
                int row = m * 16 + (lane >> 4) * 4 + j;
                float val = acc[m][n][j] + bqv;
                unsigned hb = rne_bf16(val);
                int off = row * LDQ + (col >> 3) * 16 + (col & 7);
                q_s[off]     = (u16)hb;
                q_s[off + 8] = (u16)rne_bf16(val - bf16_f(hb));
            }
        }
    __syncthreads();

    // ---------------- c[row] = q_h[row] . bk_h ----------------
    {
        int row = t >> 3, ksl = (t & 7) * 16;
        float sum = 0.f;
#pragma unroll
        for (int kk = 0; kk < 16; kk++) {
            int k = ksl + kk;
            int off = row * LDQ + (k >> 3) * 16 + (k & 7);
            float qv = bf16_f(q_s[off]) + bf16_f(q_s[off + 8]);
            sum = fmaf(qv, bk[h * DH + k], sum);
        }
        sum += __shfl_xor(sum, 1, 64);
        sum += __shfl_xor(sum, 2, 64);
        sum += __shfl_xor(sum, 4, 64);
        if ((t & 7) == 0) c_ws[(long)(r0 + row) * HH + h] = sum;
    }

    // ---------------- phase 2: g ----------------
    f32x4 acc2[2][2];
#pragma unroll
    for (int m = 0; m < 2; m++)
#pragma unroll
        for (int n = 0; n < 2; n++) acc2[m][n] = (f32x4){0.f, 0.f, 0.f, 0.f};

    auto load2 = [&](int it) {
        int nt = it >> 1, k0 = (it & 1) * 64;
#pragma unroll
        for (int i = 0; i < 4; i++) {
            int s = t + i * 256, kg = s & 7, row = s >> 3;
            long o = (long)h * (DD * DH) + (long)(nt * 128 + row) * DH + k0 + kg * 8;
            bvh[i] = *(const uint4*)&wkTh[o]; bvl[i] = *(const uint4*)&wkTl[o];
        }
    };
    load2(0);
    for (int it = 0; it < 8; it++) {
        int nt = it >> 1, k0f = (it & 1) * 64;
        __syncthreads();                 // previous Bs reads complete
#pragma unroll
        for (int i = 0; i < 4; i++) {
            int s = t + i * 256, kg = s & 7, row = s >> 3, off = row * LDW + kg * 16;
            *(uint4*)&Bs[off] = bvh[i]; *(uint4*)&Bs[off + 8] = bvl[i];
        }
        __syncthreads();
        if (it + 1 < 8) load2(it + 1);
#pragma unroll
        for (int ks = 0; ks < 2; ks++) {
            int gk = ((k0f + ks * 32) >> 3);            // k-group base
            bf16x8 ah[2], al[2], bh[2], bl[2];
#pragma unroll
            for (int m = 0; m < 2; m++) {
                int off = (m * 16 + (lane & 15)) * LDQ + (gk + (lane >> 4)) * 16;
                ah[m] = *(const bf16x8*)&q_s[off];
                al[m] = *(const bf16x8*)&q_s[off + 8];
            }
#pragma unroll
            for (int n = 0; n < 2; n++) {
                bh[n] = *(const bf16x8*)&Bs[bbase + n * 16 * LDW + ks * 64];
                bl[n] = *(const bf16x8*)&Bs[bbase + n * 16 * LDW + ks * 64 + 8];
            }
#pragma unroll
            for (int m = 0; m < 2; m++)
#pragma unroll
                for (int n = 0; n < 2; n++)
                    acc2[m][n] = __builtin_amdgcn_mfma_f32_16x16x32_bf16(ah[m], bh[n], acc2[m][n], 0, 0, 0);
#pragma unroll
            for (int m = 0; m < 2; m++)
#pragma unroll
                for (int n = 0; n < 2; n++)
                    acc2[m][n] = __builtin_amdgcn_mfma_f32_16x16x32_bf16(ah[m], bl[n], acc2[m][n], 0, 0, 0);
#pragma unroll
            for (int m = 0; m < 2; m++)
#pragma unroll
                for (int n = 0; n < 2; n++)
                    acc2[m][n] = __builtin_amdgcn_mfma_f32_16x16x32_bf16(al[m], bh[n], acc2[m][n], 0, 0, 0);
        }
        if (it & 1) {   // this nt's K (128) done -> write g tile, reset acc2
#pragma unroll
            for (int m = 0; m < 2; m++)
#pragma unroll
                for (int n = 0; n < 2; n++) {
                    int col = nt * 128 + wn * 32 + n * 16 + (lane & 15);
#pragma unroll
                    for (int j = 0; j < 4; j++) {
                        int row = m * 16 + (lane >> 4) * 4 + j;
                        g[(long)(r0 + row) * (HH * DD) + h * DD + col] = acc2[m][n][j];
                    }
                    acc2[m][n] = (f32x4){0.f, 0.f, 0.f, 0.f};
                }
        }
    }
}

// ---------------------------------------------------------------------------
// gemm_pre (proven R2 template): NT GEMM on hi/lo planes, fp32/plane output.
// ---------------------------------------------------------------------------
template<int BM, int BN>
__global__ __launch_bounds__(256)
void gemm_pre(const u16* __restrict__ Ah, const u16* __restrict__ Al, int lda, long sA,
              const u16* __restrict__ Bh, const u16* __restrict__ Bl, int ldb, long sB,
              float* __restrict__ Cf, int ldc, long sC,
              u16* __restrict__ Ch, u16* __restrict__ Cl, int ldch, long sCh,
              const float* __restrict__ bias, int sBias, int Kd)
{
    constexpr int BK  = 64;
    constexpr int LDW = 2 * BK + 8;
    constexpr int AL = BM / 32;
    constexpr int BL = BN / 32;
    constexpr int WM = BM / 2, WN = BN / 2;
    constexpr int MI = WM / 16, NI = WN / 16;

    const int z = blockIdx.z;
    Ah += (long)z * sA;  Al += (long)z * sA;
    Bh += (long)z * sB;  Bl += (long)z * sB;
    if (Cf)   Cf += (long)z * sC;
    if (Ch) { Ch += (long)z * sCh; Cl += (long)z * sCh; }
    if (bias) bias += (long)z * sBias;

    __shared__ __align__(16) u16 As[BM * LDW];
    __shared__ __align__(16) u16 Bs[BN * LDW];

    const int t    = threadIdx.x;
    const int lane = t & 63;
    const int wave = t >> 6;
    const int wm   = wave >> 1, wn = wave & 1;
    const int rbase = blockIdx.y * BM;
    const int obase = blockIdx.x * BN;

    uint4 avh[AL], avl[AL], bvh[BL], bvl[BL];
    auto loadAB = [&](int k0) {
#pragma unroll
        for (int i = 0; i < AL; i++) {
            int s = t + i * 256, kg = s & 7, row = s >> 3;
            long off = (long)(rbase + row) * lda + k0 + kg * 8;
            avh[i] = *(const uint4*)&Ah[off];
            avl[i] = *(const uint4*)&Al[off];
        }
#pragma unroll
        for (int i = 0; i < BL; i++) {
            int s = t + i * 256, kg = s & 7, row = s >> 3;
            long off = (long)(obase + row) * ldb + k0 + kg * 8;
            bvh[i] = *(const uint4*)&Bh[off];
            bvl[i] = *(const uint4*)&Bl[off];
        }
    };

    f32x4 acc[MI][NI];
#pragma unroll
    for (int m = 0; m < MI; m++)
#pragma unroll
        for (int n = 0; n < NI; n++)
            acc[m][n] = (f32x4){0.f, 0.f, 0.f, 0.f};

    const int a_base = (wm * WM + (lane & 15)) * LDW + (lane >> 4) * 16;
    const int b_base = (wn * WN + (lane & 15)) * LDW + (lane >> 4) * 16;

    loadAB(0);
    for (int k0 = 0; k0 < Kd; k0 += BK) {
        __syncthreads();
#pragma unroll
        for (int i = 0; i < AL; i++) {
            int s = t + i * 256, kg = s & 7, row = s >> 3;
            int off = row * LDW + kg * 16;
            *(uint4*)&As[off]     = avh[i];
            *(uint4*)&As[off + 8] = avl[i];
        }
#pragma unroll
        for (int i = 0; i < BL; i++) {
            int s = t + i * 256, kg = s & 7, row = s >> 3;
            int off = row * LDW + kg * 16;
            *(uint4*)&Bs[off]     = bvh[i];
            *(uint4*)&Bs[off + 8] = bvl[i];
        }
        __syncthreads();
        if (k0 + BK < Kd) loadAB(k0 + BK);

#pragma unroll
        for (int ks = 0; ks < 2; ks++) {
            bf16x8 ah[MI], al[MI], bh[NI], bl[NI];
#pragma unroll
            for (int m = 0; m < MI; m++) {
                ah[m] = *(const bf16x8*)&As[a_base + m * 16 * LDW + ks * 64];
                al[m] = *(const bf16x8*)&As[a_base + m * 16 * LDW + ks * 64 + 8];
            }
#pragma unroll
            for (int n = 0; n < NI; n++) {
                bh[n] = *(const bf16x8*)&Bs[b_base + n * 16 * LDW + ks * 64];
                bl[n] = *(const bf16x8*)&Bs[b_base + n * 16 * LDW + ks * 64 + 8];
            }
#pragma unroll
            for (int m = 0; m < MI; m++)
#pragma unroll
                for (int n = 0; n < NI; n++)
                    acc[m][n] = __builtin_amdgcn_mfma_f32_16x16x32_bf16(ah[m], bh[n], acc[m][n], 0, 0, 0);
#pragma unroll
            for (int m = 0; m < MI; m++)
#pragma unroll
                for (int n = 0; n < NI; n++)
                    acc[m][n] = __builtin_amdgcn_mfma_f32_16x16x32_bf16(ah[m], bl[n], acc[m][n], 0, 0, 0);
#pragma unroll
            for (int m = 0; m < MI; m++)
#pragma unroll
                for (int n = 0; n < NI; n++)
                    acc[m][n] = __builtin_amdgcn_mfma_f32_16x16x32_bf16(al[m], bh[n], acc[m][n], 0, 0, 0);
        }
    }

#pragma unroll
    for (int n = 0; n < NI; n++) {
        int col = obase + wn * WN + n * 16 + (lane & 15);
        float bv_ = bias ? bias[col] : 0.f;
#pragma unroll
        for (int m = 0; m < MI; m++) {
            int row0 = rbase + wm * WM + m * 16 + (lane >> 4) * 4;
#pragma unroll
            for (int j = 0; j < 4; j++) {
                float val = acc[m][n][j] + bv_;
                if (Cf) Cf[(long)(row0 + j) * ldc + col] = val;
                if (Ch) {
                    unsigned hb = rne_bf16(val);
                    long o = (long)(row0 + j) * ldch + col;
                    Ch[o] = (u16)hb;
                    Cl[o] = (u16)rne_bf16(val - bf16_f(hb));
                }
            }
        }
    }
}

// ---------------------------------------------------------------------------
// D2: fused scores -> masked online softmax -> weighted embedding sum.
// c (= q_h . bk_h) precomputed in D1; q not needed here at all.
// ---------------------------------------------------------------------------
__global__ __launch_bounds__(256)
void attn_fused(const float* __restrict__ ne,    // [BN][32][512]
                const int*   __restrict__ mask,  // [BN][32]
                const float* __restrict__ c_ws,  // [BN][4]
                const float* __restrict__ g,     // [BN][4][512]
                u16* __restrict__ wh,            // [BN][4][512] bf16 hi
                u16* __restrict__ wl)            // [BN][4][512] bf16 lo
{
    const int bn   = blockIdx.x;
    const int t    = threadIdx.x;
    const int wave = t >> 6;
    const int lane = t & 63;

    __shared__ __align__(16) float ne_s[16][516];
    __shared__ __align__(16) float g_s[HH * DD];
    __shared__ float part[4][16][HH];
    __shared__ float p_s[HH][16];
    __shared__ float c_s[HH];
    __shared__ float m_s[HH], l_s[HH], alpha_s[HH];

    {
        const float4* gs = (const float4*)(g + (long)bn * (HH * DD));
        float4 v0 = gs[t];
        float4 v1 = gs[t + 256];
        *(float4*)&g_s[t * 4]         = v0;
        *(float4*)&g_s[(t + 256) * 4] = v1;
    }
    if (t < HH) {
        c_s[t] = c_ws[(long)bn * HH + t];
        m_s[t] = -__builtin_inff(); l_s[t] = 0.f;
    }

    float wacc[8] = {};
    const int h_own = t >> 6;
    const int dlo   = (t & 63) * 4;      // cols dlo..+3 and 256+dlo..+3 (dense b128)
    const int kk    = t & 15;
    const int rep   = t >> 4;

    for (int ch = 0; ch < 2; ch++) {
        __syncthreads();
        {
            const float4* src = (const float4*)(ne + (long)bn * (KK_N * DD) + ch * (16 * DD));
#pragma unroll
            for (int i = 0; i < 8; i++) {
                int f = i * 256 + t;
                float4 v = src[f];
                *(float4*)&ne_s[f >> 7][(f & 127) * 4] = v;
            }
        }
        __syncthreads();
        {
            float acc[HH] = {};
#pragma unroll
            for (int i = 0; i < 8; i++) {
                float4 nv = *(const float4*)&ne_s[kk][rep * 32 + i * 4];
#pragma unroll
                for (int h = 0; h < HH; h++) {
                    float4 gv = *(const float4*)&g_s[h * DD + rep * 32 + i * 4];
                    acc[h] = fmaf(nv.x, gv.x, acc[h]);
                    acc[h] = fmaf(nv.y, gv.y, acc[h]);
                    acc[h] = fmaf(nv.z, gv.z, acc[h]);
                    acc[h] = fmaf(nv.w, gv.w, acc[h]);
                }
            }
#pragma unroll
            for (int h = 0; h < HH; h++) {
                acc[h] += __shfl_xor(acc[h], 16, 64);
                acc[h] += __shfl_xor(acc[h], 32, 64);
            }
            if ((t & 48) == 0) {
#pragma unroll
                for (int h = 0; h < HH; h++) part[wave][kk][h] = acc[h];
            }
        }
        __syncthreads();
        if (t < 64) {
            int k_i = t & 15, h = t >> 4;
            float s = part[0][k_i][h] + part[1][k_i][h] + part[2][k_i][h]
                    + part[3][k_i][h] + c_s[h];
            if (mask[(long)bn * KK_N + ch * 16 + k_i] == 0) s = -1.0e9f;
            float mx = s;
#pragma unroll
            for (int off = 8; off >= 1; off >>= 1)
                mx = fmaxf(mx, __shfl_xor(mx, off, 64));
            float m_old = m_s[h];
            float m_new = fmaxf(m_old, mx);
            float p = expf(s - m_new);
            float sm = p;
#pragma unroll
            for (int off = 8; off >= 1; off >>= 1)
                sm += __shfl_xor(sm, off, 64);
            p_s[h][k_i] = p;
            if (k_i == 0) {
                float alpha = expf(m_old - m_new);
                alpha_s[h] = alpha;
                l_s[h] = l_s[h] * alpha + sm;
                m_s[h] = m_new;
            }
        }
        __syncthreads();
        {
            float alpha = alpha_s[h_own];
#pragma unroll
            for (int j = 0; j < 8; j++) wacc[j] *= alpha;
#pragma unroll
            for (int k2 = 0; k2 < 16; k2++) {
                float pk = p_s[h_own][k2];
                float4 n0 = *(const float4*)&ne_s[k2][dlo];
                float4 n1 = *(const float4*)&ne_s[k2][256 + dlo];
                wacc[0] = fmaf(pk, n0.x, wacc[0]);
                wacc[1] = fmaf(pk, n0.y, wacc[1]);
                wacc[2] = fmaf(pk, n0.z, wacc[2]);
                wacc[3] = fmaf(pk, n0.w, wacc[3]);
                wacc[4] = fmaf(pk, n1.x, wacc[4]);
                wacc[5] = fmaf(pk, n1.y, wacc[5]);
                wacc[6] = fmaf(pk, n1.z, wacc[6]);
                wacc[7] = fmaf(pk, n1.w, wacc[7]);
            }
        }
    }
    float rl = 1.0f / l_s[h_own];
    long b0 = (long)bn * (HH * DD) + h_own * DD + dlo;
    unsigned hw[8], lw[8];
#pragma unroll
    for (int j = 0; j < 8; j++) {
        float val = wacc[j] * rl;
        hw[j] = rne_bf16(val);
        lw[j] = rne_bf16(val - bf16_f(hw[j]));
    }
    *(uint2*)&wh[b0]       = make_uint2(hw[0] | (hw[1] << 16), hw[2] | (hw[3] << 16));
    *(uint2*)&wl[b0]       = make_uint2(lw[0] | (lw[1] << 16), lw[2] | (lw[3] << 16));
    *(uint2*)&wh[b0 + 256] = make_uint2(hw[4] | (hw[5] << 16), hw[6] | (hw[7] << 16));
    *(uint2*)&wl[b0 + 256] = make_uint2(lw[4] | (lw[5] << 16), lw[6] | (lw[7] << 16));
}

// ---------------------------------------------------------------------------
extern "C" void kernel_launch(void* const* d_in, const int* in_sizes, int n_in,
                              void* d_out, int out_size, void* d_ws, size_t ws_size,
                              hipStream_t stream) {
    (void)in_sizes; (void)n_in; (void)out_size; (void)ws_size;
    const float* ne  = (const float*)d_in[0];
    const int*   msk = (const int*)  d_in[1];
    const float* x   = (const float*)d_in[2];
    const float* Wq  = (const float*)d_in[3];
    const float* bq  = (const float*)d_in[4];
    const float* Wk  = (const float*)d_in[5];
    const float* bk  = (const float*)d_in[6];
    const float* Wv  = (const float*)d_in[7];
    const float* bv  = (const float*)d_in[8];
    float* out = (float*)d_out;

    const long NQ = (long)BN_TOT * DD;        // 2,097,152
    const long NW = (long)DD * DD;            //   262,144
    const long NG = (long)BN_TOT * HH * DD;   // 8,388,608

    char* ws = (char*)d_ws;
    u16* xh   = (u16*)ws;              ws += NQ * 2;
    u16* xl   = (u16*)ws;              ws += NQ * 2;
    u16* wqh  = (u16*)ws;              ws += NW * 2;
    u16* wql  = (u16*)ws;              ws += NW * 2;
    u16* wvh  = (u16*)ws;              ws += NW * 2;
    u16* wvl  = (u16*)ws;              ws += NW * 2;
    u16* wkTh = (u16*)ws;              ws += NW * 2;
    u16* wkTl = (u16*)ws;              ws += NW * 2;
    u16* wneh = (u16*)ws;              ws += NG * 2;
    u16* wnel = (u16*)ws;              ws += NG * 2;
    float* g_ws = (float*)ws;          ws += NG * 4;   // 32 MB
    float* c_ws = (float*)ws;          // [4096][4]

    dim3 blk(256);
    // P0: all conversions + WkT transpose (one dispatch)
    prep<<<dim3(2624), blk, 0, stream>>>(
        (const float4*)x,  xh,  xl,
        (const float4*)Wq, wqh, wql,
        (const float4*)Wv, wvh, wvl,
        Wk, wkTh, wkTl);
    // D1: fused q + c + g   (grid 128 row-tiles x 4 heads)
    qg_fused<<<dim3(BN_TOT / 32, HH), blk, 0, stream>>>(
        xh, xl, wqh, wql, wkTh, wkTl, bq, bk, g_ws, c_ws);
    // D2: attention
    attn_fused<<<dim3(BN_TOT), blk, 0, stream>>>(ne, msk, c_ws, g_ws, wneh, wnel);
    // D3: out[:,h*128:] = wne_h @ Wv_h^T + bv_h   (BM=32 -> grid 512, 3 blk/CU)
    gemm_pre<32, 128><<<dim3(1, BN_TOT / 32, HH), blk, 0, stream>>>(
        wneh, wnel, HH * DD, DD, wvh, wvl, DD, (long)DH * DD,
        out, DD, DH, nullptr, nullptr, 0, 0, bv, DH, DD);
}

// Round 4
// 483.766 us; speedup vs baseline: 1.0634x; 1.0418x over previous
//
#include <hip/hip_runtime.h>

// Problem constants
#define DD   512
#define KK_N 32
#define HH   4
#define DH   128
#define BN_TOT 4096

typedef __bf16 bf16x8 __attribute__((ext_vector_type(8)));
typedef float  f32x4  __attribute__((ext_vector_type(4)));

__device__ __forceinline__ unsigned rne_bf16(float x) {
    unsigned u = __float_as_uint(x);
    return (u + 0x7fffu + ((u >> 16) & 1u)) >> 16;
}

// ---------------------------------------------------------------------------
// One-time prep: WkT[h][o][k] = Wk[h*128 + k][o]  (fp32, 1 MB total)
// grid (16, 4). LDS-tiled transpose.  (R1-verbatim)
// ---------------------------------------------------------------------------
__global__ __launch_bounds__(256)
void prep_wkT(const float* __restrict__ Wk, float* __restrict__ WkT)
{
    __shared__ float tile[32][DH + 1];
    const int h = blockIdx.y, o0 = blockIdx.x * 32, t = threadIdx.x;
#pragma unroll
    for (int r = 0; r < 16; r++) {
        int k = (t >> 5) + r * 8;                       // 0..127
        tile[t & 31][k] = Wk[(long)(h * DH + k) * DD + o0 + (t & 31)];
    }
    __syncthreads();
#pragma unroll
    for (int r = 0; r < 16; r++) {
        int ol = (t >> 7) + r * 2;                      // 0..31
        WkT[((long)h * DD + o0 + ol) * DH + (t & 127)] = tile[ol][t & 127];
    }
}

// ---------------------------------------------------------------------------
// bf16x2-split MFMA GEMM (NT) — R1-verbatim (measured best at 447):
//   C[r][o] = sum_k A[r][k]*B[o][k] (+bias[o]); fp32 in/out; hi/lo bf16 split
//   converted during LDS staging; Ah*Bh + Ah*Bl + Al*Bh on 16x16x32 MFMA.
// ---------------------------------------------------------------------------
template<int BM, int BN>
__global__ __launch_bounds__(256)
void gemm_bf16x2(const float* __restrict__ A, int lda, long sA,
                 const float* __restrict__ B, int ldb, long sB,
                 float*       __restrict__ C, int ldc, long sC,
                 const float* __restrict__ bias, int sBias,
                 int Kd)
{
    constexpr int BK  = 64;
    constexpr int LDW = 2 * BK + 8;                 // 136 bf16 per row
    constexpr int A_LOADS = BM * BK / 1024;         // float4 rounds of 256 thr
    constexpr int B_LOADS = BN * BK / 1024;
    constexpr int WM = BM / 2, WN = BN / 2;
    constexpr int MI = WM / 16, NI = WN / 16;

    const int z = blockIdx.z;
    A += (long)z * sA;
    B += (long)z * sB;
    C += (long)z * sC;
    if (bias) bias += (long)z * sBias;

    __shared__ __align__(16) unsigned short As[BM * LDW];
    __shared__ __align__(16) unsigned short Bs[BN * LDW];

    const int t    = threadIdx.x;
    const int lane = t & 63;
    const int wave = t >> 6;
    const int wm   = wave >> 1, wn = wave & 1;
    const int rbase = blockIdx.y * BM;
    const int obase = blockIdx.x * BN;

    float4 areg[A_LOADS], breg[B_LOADS];
    auto loadAB = [&](int k0) {
#pragma unroll
        for (int i = 0; i < A_LOADS; i++) {
            int s = t + i * 256, k4 = s & 15, row = s >> 4;
            areg[i] = *(const float4*)&A[(long)(rbase + row) * lda + k0 + k4 * 4];
        }
#pragma unroll
        for (int i = 0; i < B_LOADS; i++) {
            int s = t + i * 256, k4 = s & 15, row = s >> 4;
            breg[i] = *(const float4*)&B[(long)(obase + row) * ldb + k0 + k4 * 4];
        }
    };
    auto cvt_store = [&](unsigned short* dst, float4 v, int row, int k4) {
        unsigned h0 = rne_bf16(v.x), h1 = rne_bf16(v.y);
        unsigned h2 = rne_bf16(v.z), h3 = rne_bf16(v.w);
        float l0 = v.x - __uint_as_float(h0 << 16);
        float l1 = v.y - __uint_as_float(h1 << 16);
        float l2 = v.z - __uint_as_float(h2 << 16);
        float l3 = v.w - __uint_as_float(h3 << 16);
        int off = row * LDW + (k4 >> 1) * 16 + (k4 & 1) * 4;
        uint2 hw = make_uint2(h0 | (h1 << 16), h2 | (h3 << 16));
        uint2 lw = make_uint2(rne_bf16(l0) | (rne_bf16(l1) << 16),
                              rne_bf16(l2) | (rne_bf16(l3) << 16));
        *(uint2*)&dst[off]     = hw;   // hi half of this 8-k group
        *(uint2*)&dst[off + 8] = lw;   // lo half
    };

    f32x4 acc[MI][NI];
#pragma unroll
    for (int m = 0; m < MI; m++)
#pragma unroll
        for (int n = 0; n < NI; n++)
            acc[m][n] = (f32x4){0.f, 0.f, 0.f, 0.f};

    // fragment base: row/col = (lane&15) within 16x16, k-block = (lane>>4)*8
    const int a_base = (wm * WM + (lane & 15)) * LDW + (lane >> 4) * 16;
    const int b_base = (wn * WN + (lane & 15)) * LDW + (lane >> 4) * 16;

    loadAB(0);
    for (int k0 = 0; k0 < Kd; k0 += BK) {
        __syncthreads();
#pragma unroll
        for (int i = 0; i < A_LOADS; i++) { int s = t + i * 256; cvt_store(As, areg[i], s >> 4, s & 15); }
#pragma unroll
        for (int i = 0; i < B_LOADS; i++) { int s = t + i * 256; cvt_store(Bs, breg[i], s >> 4, s & 15); }
        __syncthreads();
        if (k0 + BK < Kd) loadAB(k0 + BK);   // prefetch overlaps compute

#pragma unroll
        for (int ks = 0; ks < 2; ks++) {
            bf16x8 ah[MI], al[MI], bh[NI], bl[NI];
#pragma unroll
            for (int m = 0; m < MI; m++) {
                ah[m] = *(const bf16x8*)&As[a_base + m * 16 * LDW + ks * 64];
                al[m] = *(const bf16x8*)&As[a_base + m * 16 * LDW + ks * 64 + 8];
            }
#pragma unroll
            for (int n = 0; n < NI; n++) {
                bh[n] = *(const bf16x8*)&Bs[b_base + n * 16 * LDW + ks * 64];
                bl[n] = *(const bf16x8*)&Bs[b_base + n * 16 * LDW + ks * 64 + 8];
            }
#pragma unroll
            for (int m = 0; m < MI; m++)
#pragma unroll
                for (int n = 0; n < NI; n++)
                    acc[m][n] = __builtin_amdgcn_mfma_f32_16x16x32_bf16(ah[m], bh[n], acc[m][n], 0, 0, 0);
#pragma unroll
            for (int m = 0; m < MI; m++)
#pragma unroll
                for (int n = 0; n < NI; n++)
                    acc[m][n] = __builtin_amdgcn_mfma_f32_16x16x32_bf16(ah[m], bl[n], acc[m][n], 0, 0, 0);
#pragma unroll
            for (int m = 0; m < MI; m++)
#pragma unroll
                for (int n = 0; n < NI; n++)
                    acc[m][n] = __builtin_amdgcn_mfma_f32_16x16x32_bf16(al[m], bh[n], acc[m][n], 0, 0, 0);
        }
    }

    // epilogue: C/D layout col = lane&15, row = (lane>>4)*4 + reg  [m89-verified]
#pragma unroll
    for (int n = 0; n < NI; n++) {
        int col = obase + wn * WN + n * 16 + (lane & 15);
        float bv_ = bias ? bias[col] : 0.f;
#pragma unroll
        for (int m = 0; m < MI; m++) {
            int row0 = rbase + wm * WM + m * 16 + (lane >> 4) * 4;
#pragma unroll
            for (int j = 0; j < 4; j++)
                C[(long)(row0 + j) * ldc + col] = acc[m][n][j] + bv_;
        }
    }
}

// ---------------------------------------------------------------------------
// Fused scores -> masked online softmax -> attention-weighted embedding sum.
// One block per (b,n). wne may alias g (read fully before written, same block).
// R1 base + two local changes:
//   (1) ne chunk double-buffer: chunk ch+1's global loads prefetch into regs
//       during chunk ch's compute phases (hides ~900cyc HBM latency).
//   (2) weighted phase: lane l owns cols {4l..4l+3} and {256+4l..256+4l+3} so
//       each 8-lane cluster's ds_read_b128 covers all 32 banks (was 16-way).
// ---------------------------------------------------------------------------
__global__ __launch_bounds__(256)
void attn_fused(const float* __restrict__ ne,    // [BN][32][512]
                const int*   __restrict__ mask,  // [BN][32]
                const float* __restrict__ q,     // [BN][512]
                const float* g,                  // [BN][4][512]  (no restrict: aliases wne)
                const float* __restrict__ bk,    // [512]
                float* wne)                      // [BN][4][512]
{
    const int bn   = blockIdx.x;
    const int t    = threadIdx.x;
    const int wave = t >> 6;
    const int lane = t & 63;

    __shared__ __align__(16) float ne_s[16][516];   // chunk of 16 neighbors, padded
    __shared__ __align__(16) float g_s[HH * DD];
    __shared__ float part[4][16][HH];               // [wave][k][h]
    __shared__ float p_s[HH][16];
    __shared__ float c_s[HH];
    __shared__ float m_s[HH], l_s[HH], alpha_s[HH];

    // stage g (query-side projected vectors), 2048 floats
    {
        const float4* gs = (const float4*)(g + (long)bn * (HH * DD));
        float4 v0 = gs[t];
        float4 v1 = gs[t + 256];
        *(float4*)&g_s[t * 4]         = v0;
        *(float4*)&g_s[(t + 256) * 4] = v1;
    }
    // c[h] = q_h . bk_h   (wave w handles head w; 64 lanes x 2 elems = 128)
    {
        float2 q2 = *(const float2*)&q[(long)bn * DD + wave * DH + lane * 2];
        float2 b2 = *(const float2*)&bk[wave * DH + lane * 2];
        float cp = q2.x * b2.x + q2.y * b2.y;
#pragma unroll
        for (int off = 32; off >= 1; off >>= 1)
            cp += __shfl_xor(cp, off, 64);
        if (lane == 0) c_s[wave] = cp;
    }
    if (t < HH) { m_s[t] = -__builtin_inff(); l_s[t] = 0.f; }

    float wacc[8] = {};
    const int h_own = t >> 6;            // head owned in weighted-sum phase
    const int dlo   = (t & 63) * 4;      // cols dlo..+3 and 256+dlo..+3
    const int kk    = t & 15;            // neighbor within chunk (scores phase)
    const int rep   = t >> 4;            // D-slice 32 floats (scores phase)

    const float4* src = (const float4*)(ne + (long)bn * (KK_N * DD));
    float4 pre[8];
    // preload chunk 0 (16 rows, 32 KB) into registers
#pragma unroll
    for (int i = 0; i < 8; i++) pre[i] = src[i * 256 + t];

    for (int ch = 0; ch < 2; ch++) {
        __syncthreads();            // g_s staged / prev weighted's ne_s reads done
        // commit prefetched chunk to LDS
#pragma unroll
        for (int i = 0; i < 8; i++) {
            int f = i * 256 + t;
            *(float4*)&ne_s[f >> 7][(f & 127) * 4] = pre[i];
        }
        __syncthreads();
        // prefetch next chunk (overlaps scores + softmax + weighted)
        if (ch == 0) {
#pragma unroll
            for (int i = 0; i < 8; i++) pre[i] = src[512 * 4 + i * 256 + t];
        }
        // scores: 16 k x 4 h dot products of length 512, split 16 ways over D
        {
            float acc[HH] = {};
#pragma unroll
            for (int i = 0; i < 8; i++) {
                float4 nv = *(const float4*)&ne_s[kk][rep * 32 + i * 4];
#pragma unroll
                for (int h = 0; h < HH; h++) {
                    float4 gv = *(const float4*)&g_s[h * DD + rep * 32 + i * 4];
                    acc[h] = fmaf(nv.x, gv.x, acc[h]);
                    acc[h] = fmaf(nv.y, gv.y, acc[h]);
                    acc[h] = fmaf(nv.z, gv.z, acc[h]);
                    acc[h] = fmaf(nv.w, gv.w, acc[h]);
                }
            }
#pragma unroll
            for (int h = 0; h < HH; h++) {
                acc[h] += __shfl_xor(acc[h], 16, 64);
                acc[h] += __shfl_xor(acc[h], 32, 64);
            }
            if ((t & 48) == 0) {
#pragma unroll
                for (int h = 0; h < HH; h++) part[wave][kk][h] = acc[h];
            }
        }
        __syncthreads();
        // online softmax update (wave 0 only; lanes: k_i = bits 0..3, h = bits 4..5)
        if (t < 64) {
            int k_i = t & 15, h = t >> 4;
            float s = part[0][k_i][h] + part[1][k_i][h] + part[2][k_i][h]
                    + part[3][k_i][h] + c_s[h];
            if (mask[(long)bn * KK_N + ch * 16 + k_i] == 0) s = -1.0e9f;
            float mx = s;
#pragma unroll
            for (int off = 8; off >= 1; off >>= 1)
                mx = fmaxf(mx, __shfl_xor(mx, off, 64));
            float m_old = m_s[h];
            float m_new = fmaxf(m_old, mx);
            float p = expf(s - m_new);
            float sm = p;
#pragma unroll
            for (int off = 8; off >= 1; off >>= 1)
                sm += __shfl_xor(sm, off, 64);
            p_s[h][k_i] = p;
            if (k_i == 0) {
                float alpha = expf(m_old - m_new);
                alpha_s[h] = alpha;
                l_s[h] = l_s[h] * alpha + sm;
                m_s[h] = m_new;
            }
        }
        __syncthreads();
        // weighted accumulate: thread owns (h_own, cols dlo..+3 and 256+dlo..+3)
        {
            float alpha = alpha_s[h_own];
#pragma unroll
            for (int j = 0; j < 8; j++) wacc[j] *= alpha;
#pragma unroll
            for (int k2 = 0; k2 < 16; k2++) {
                float pk = p_s[h_own][k2];
                float4 n0 = *(const float4*)&ne_s[k2][dlo];
                float4 n1 = *(const float4*)&ne_s[k2][256 + dlo];
                wacc[0] = fmaf(pk, n0.x, wacc[0]);
                wacc[1] = fmaf(pk, n0.y, wacc[1]);
                wacc[2] = fmaf(pk, n0.z, wacc[2]);
                wacc[3] = fmaf(pk, n0.w, wacc[3]);
                wacc[4] = fmaf(pk, n1.x, wacc[4]);
                wacc[5] = fmaf(pk, n1.y, wacc[5]);
                wacc[6] = fmaf(pk, n1.z, wacc[6]);
                wacc[7] = fmaf(pk, n1.w, wacc[7]);
            }
        }
    }
    // finalize: normalize and write wne (fp32, float4)
    float rl = 1.0f / l_s[h_own];
    float4 o0 = make_float4(wacc[0] * rl, wacc[1] * rl, wacc[2] * rl, wacc[3] * rl);
    float4 o1 = make_float4(wacc[4] * rl, wacc[5] * rl, wacc[6] * rl, wacc[7] * rl);
    float* dst = wne + (long)bn * (HH * DD) + h_own * DD + dlo;
    *(float4*)&dst[0]   = o0;
    *(float4*)&dst[256] = o1;
}

// ---------------------------------------------------------------------------
extern "C" void kernel_launch(void* const* d_in, const int* in_sizes, int n_in,
                              void* d_out, int out_size, void* d_ws, size_t ws_size,
                              hipStream_t stream) {
    (void)in_sizes; (void)n_in; (void)out_size; (void)ws_size;
    const float* ne  = (const float*)d_in[0];
    const int*   msk = (const int*)  d_in[1];
    const float* x   = (const float*)d_in[2];
    const float* Wq  = (const float*)d_in[3];
    const float* bq  = (const float*)d_in[4];
    const float* Wk  = (const float*)d_in[5];
    const float* bk  = (const float*)d_in[6];
    const float* Wv  = (const float*)d_in[7];
    const float* bv  = (const float*)d_in[8];
    float* out = (float*)d_out;

    float* q_ws = (float*)d_ws;                       // [4096][512]      8 MB
    float* g_ws = q_ws + (long)BN_TOT * DD;           // [4096][4][512]  32 MB (g, then wne)
    float* wkT  = g_ws + (long)BN_TOT * HH * DD;      // [4][512][128]    1 MB

    dim3 blk(256);
    // 0) WkT[h][o][k] = Wk[h*128+k][o]  (makes step 2 an NT GEMM)
    prep_wkT<<<dim3(16, HH), blk, 0, stream>>>(Wk, wkT);
    // 1) q = x @ Wq^T + bq            M=4096 N=512 K=512; BM=32 -> 512 blocks (3/CU)
    gemm_bf16x2<32, 128><<<dim3(DD / 128, BN_TOT / 32, 1), blk, 0, stream>>>(
        x, DD, 0, Wq, DD, 0, q_ws, DD, 0, bq, 0, DD);
    // 2) g[:,h,:] = q_h @ WkT[h]^T    per head: M=4096 N=512 K=128; 1024 blocks
    gemm_bf16x2<64, 128><<<dim3(DD / 128, BN_TOT / 64, HH), blk, 0, stream>>>(
        q_ws, DD, DH, wkT, DH, (long)DD * DH, g_ws, HH * DD, DD, nullptr, 0, DH);
    // 3) fused scores/softmax/weighted-sum -> wne (aliases g_ws)
    attn_fused<<<dim3(BN_TOT), blk, 0, stream>>>(ne, msk, q_ws, g_ws, bk, g_ws);
    // 4) out[:,h*128:] = wne_h @ Wv_h^T + bv_h   per head: BM=32 -> 512 blocks (3/CU)
    gemm_bf16x2<32, 128><<<dim3(1, BN_TOT / 32, HH), blk, 0, stream>>>(
        g_ws, HH * DD, DD, Wv, DD, (long)DH * DD, out, DD, DH, bv, DH, DD);
}